// Round 1
// baseline (294.794 us; speedup 1.0000x reference)
//
#include <hip/hip_runtime.h>
#include <cstdint>

// Problem constants (fixed by setup_inputs)
#define BDIM 8192
#define DDIM 128
#define BI 64            // i-rows (compacted, censor==1) per block
#define BJ 64            // j-rows per LDS tile
#define JSPLIT 8         // j-dimension split across blocks
#define JCHUNK (BDIM / JSPLIT)   // 1024 j per block

// ws layout (bytes)
#define Z_OFF 0
#define Z_BYTES (BDIM * DDIM * 4)          // 4194304
#define ROWLIST_OFF Z_BYTES                 // 4194304
#define SD_OFF (ROWLIST_OFF + BDIM * 4)     // 4227072
#define SN_OFF (SD_OFF + BDIM * 4)          // 4259840
#define CNT_OFF (SN_OFF + BDIM * 4)         // 4292608

// Kernel 1: L2-normalize rows (torch F.normalize semantics: e / max(||e||, eps))
// + compact the list of rows with censor==1 (only those contribute to the loss).
__global__ __launch_bounds__(256) void ck_normalize(
    const float* __restrict__ emb, const int* __restrict__ censor,
    float* __restrict__ z, int* __restrict__ rowlist, int* __restrict__ cnt)
{
  const int lane = threadIdx.x & 63;
  const int row  = (blockIdx.x << 2) + (threadIdx.x >> 6);  // 4 rows/block, 1 wave/row
  const float e0 = emb[row * DDIM + lane];
  const float e1 = emb[row * DDIM + 64 + lane];
  float ss = e0 * e0 + e1 * e1;
#pragma unroll
  for (int m = 1; m < 64; m <<= 1) ss += __shfl_xor(ss, m, 64);
  const float nrm = fmaxf(sqrtf(ss), 1e-12f);
  z[row * DDIM + lane]      = e0 / nrm;
  z[row * DDIM + 64 + lane] = e1 / nrm;
  if (lane == 0 && censor[row] == 1) {
    const int p = atomicAdd(cnt, 1);
    rowlist[p] = row;
  }
}

// Kernel 2: fused sim + masked exp-sum reductions.
// Block = 256 threads = (tx 0..15 [j]) x (ty 0..15 [i]); micro-tile 4x4.
// i rows: ty*4+a (compacted/gathered). j rows: tx+16*b (contiguous global rows).
// LDS tiles are XOR-swizzled at float4 granularity: logical (row,c4) stored at
// row*32 + (c4 ^ (row & 31)). Keeps 16B alignment, kills bank conflicts:
//   B-reads: 16 distinct addrs -> 2-way max (free); A-reads: 4-addr broadcast.
__global__ __launch_bounds__(256, 2) void ck_main(
    const float* __restrict__ z, const int* __restrict__ rowlist,
    const int* __restrict__ cntp, const int* __restrict__ times,
    float* __restrict__ Sd, float* __restrict__ Sn)
{
  __shared__ float zi[BI * DDIM];   // 32 KB
  __shared__ float zj[BJ * DDIM];   // 32 KB  (total exactly 64 KB -> 2 blocks/CU)

  const int tid = threadIdx.x;
  const int it = blockIdx.x >> 3;          // i-tile index (compacted space)
  const int js = blockIdx.x & (JSPLIT - 1);
  const int cnt = *cntp;
  const int ibase = it * BI;
  if (ibase >= cnt) return;                // empty tile: exit

  const int tx = tid & 15;
  const int ty = tid >> 4;

  const float4* z4 = (const float4*)z;
  float4* zi4 = (float4*)zi;
  float4* zj4 = (float4*)zj;

  // per-thread i-row metadata (registers; invalid rows -> rI=-1, never matches)
  int rI[4], tI[4];
#pragma unroll
  for (int a = 0; a < 4; ++a) {
    const int idx = ibase + ty * 4 + a;
    const bool v = (idx < cnt);
    rI[a] = v ? rowlist[idx] : -1;
    tI[a] = v ? times[rI[a]] : -1000000;   // guarantees |tdiff| >= 365
  }

  // stage zi (gathered rows), swizzled
  for (int u = tid; u < BI * 32; u += 256) {
    const int row = u >> 5, c4 = u & 31;
    const int idx = ibase + row;
    float4 v = make_float4(0.f, 0.f, 0.f, 0.f);
    if (idx < cnt) v = z4[rowlist[idx] * 32 + c4];
    zi4[row * 32 + (c4 ^ (row & 31))] = v;
  }

  float sd[4] = {0.f, 0.f, 0.f, 0.f};
  float sn[4] = {0.f, 0.f, 0.f, 0.f};

  const int jstart = js * JCHUNK;
  for (int jt = 0; jt < JCHUNK; jt += BJ) {
    const int jbase = jstart + jt;
    __syncthreads();  // protect zj from previous tile's readers (also covers zi 1st iter)
    for (int u = tid; u < BJ * 32; u += 256) {
      const int row = u >> 5, c4 = u & 31;
      zj4[row * 32 + (c4 ^ (row & 31))] = z4[(jbase + row) * 32 + c4];
    }
    __syncthreads();

    float acc[4][4] = {{0.f}};
#pragma unroll 4
    for (int k4 = 0; k4 < 32; ++k4) {
      float4 av[4], bv[4];
#pragma unroll
      for (int a = 0; a < 4; ++a) {
        const int row = ty * 4 + a;
        av[a] = zi4[row * 32 + (k4 ^ (row & 31))];
      }
#pragma unroll
      for (int b = 0; b < 4; ++b) {
        const int row = tx + 16 * b;
        bv[b] = zj4[row * 32 + (k4 ^ (row & 31))];
      }
#pragma unroll
      for (int a = 0; a < 4; ++a)
#pragma unroll
        for (int b = 0; b < 4; ++b) {
          acc[a][b] += av[a].x * bv[b].x + av[a].y * bv[b].y +
                       av[a].z * bv[b].z + av[a].w * bv[b].w;
        }
    }

    // epilogue: s = dot/T; fixed-offset exp-sums. exp(s-10) in [e^-20, 1].
    int tJ[4];
#pragma unroll
    for (int b = 0; b < 4; ++b) tJ[b] = times[jbase + tx + 16 * b];
#pragma unroll
    for (int a = 0; a < 4; ++a) {
#pragma unroll
      for (int b = 0; b < 4; ++b) {
        const int jg = jbase + tx + 16 * b;
        const float s = acc[a][b] * 10.0f;
        float p = __expf(s - 10.0f);
        if (jg == rI[a]) p = 0.0f;         // diagonal mask (exp(NEG-max)==0 in ref)
        sd[a] += p;
        int td = tI[a] - tJ[b];
        td = (td < 0) ? -td : td;
        if (td < 365) sn[a] += p;          // positive mask (j!=i already handled)
      }
    }
  }

  // reduce over tx (lane bits 0..3), then one atomicAdd per (row, block)
#pragma unroll
  for (int a = 0; a < 4; ++a) {
    float d = sd[a], n = sn[a];
#pragma unroll
    for (int m = 1; m <= 8; m <<= 1) {
      d += __shfl_xor(d, m, 64);
      n += __shfl_xor(n, m, 64);
    }
    if (tx == 0 && rI[a] >= 0) {
      atomicAdd(&Sd[rI[a]], d);
      atomicAdd(&Sn[rI[a]], n);
    }
  }
}

// Kernel 3: per-row loss = log(Sd) - log(Sn) (== denom - num), deterministic reduce.
__global__ __launch_bounds__(1024) void ck_finalize(
    const float* __restrict__ Sd, const float* __restrict__ Sn,
    const int* __restrict__ censor, float* __restrict__ out)
{
  __shared__ float ssum[1024];
  __shared__ float scnt[1024];
  const int tid = threadIdx.x;
  float lsum = 0.f, lcnt = 0.f;
  for (int r = tid; r < BDIM; r += 1024) {
    const float n = Sn[r];
    if (censor[r] == 1 && n > 0.f) {
      lsum += logf(Sd[r]) - logf(n);
      lcnt += 1.f;
    }
  }
  ssum[tid] = lsum;
  scnt[tid] = lcnt;
  __syncthreads();
  for (int s = 512; s > 0; s >>= 1) {
    if (tid < s) { ssum[tid] += ssum[tid + s]; scnt[tid] += scnt[tid + s]; }
    __syncthreads();
  }
  if (tid == 0) out[0] = (scnt[0] > 0.f) ? ssum[0] / fmaxf(scnt[0], 1.f) : 0.f;
}

extern "C" void kernel_launch(void* const* d_in, const int* in_sizes, int n_in,
                              void* d_out, int out_size, void* d_ws, size_t ws_size,
                              hipStream_t stream) {
  const float* emb   = (const float*)d_in[0];
  const int* times   = (const int*)d_in[1];
  const int* censor  = (const int*)d_in[2];
  float* out = (float*)d_out;

  char* ws = (char*)d_ws;
  float* z     = (float*)(ws + Z_OFF);
  int* rowlist = (int*)(ws + ROWLIST_OFF);
  float* Sd    = (float*)(ws + SD_OFF);
  float* Sn    = (float*)(ws + SN_OFF);
  int* cnt     = (int*)(ws + CNT_OFF);

  // zero Sd, Sn, cnt in one contiguous memset (ws is poisoned 0xAA)
  hipMemsetAsync(ws + SD_OFF, 0, BDIM * 4 * 2 + 4, stream);
  ck_normalize<<<BDIM / 4, 256, 0, stream>>>(emb, censor, z, rowlist, cnt);
  ck_main<<<(BDIM / BI) * JSPLIT, 256, 0, stream>>>(z, rowlist, cnt, times, Sd, Sn);
  ck_finalize<<<1, 1024, 0, stream>>>(Sd, Sn, censor, out);
}

// Round 2
// 271.124 us; speedup vs baseline: 1.0873x; 1.0873x over previous
//
#include <hip/hip_runtime.h>
#include <cstdint>

#define BDIM 8192
#define DDIM 128

// ws layout (bytes)
#define ZH_OFF 0
#define ZL_OFF (BDIM * DDIM * 2)                 // 2 MB
#define ROWLIST_OFF (ZL_OFF + BDIM * DDIM * 2)   // 4 MB
#define SD_OFF (ROWLIST_OFF + BDIM * 4)
#define SN_OFF (SD_OFF + BDIM * 4)
#define CNT_OFF (SN_OFF + BDIM * 4)

typedef __attribute__((ext_vector_type(8))) short bf16x8;   // 8 bf16 = 4 VGPRs
typedef __attribute__((ext_vector_type(4))) float f32x4;

__device__ __forceinline__ short f2bf(float f) {          // RTN-even fp32->bf16
  unsigned u = __float_as_uint(f);
  unsigned r = (u + 0x7fffu + ((u >> 16) & 1u)) >> 16;
  return (short)r;
}
__device__ __forceinline__ float bf2f(short h) {
  return __uint_as_float(((unsigned)(unsigned short)h) << 16);
}
__device__ __forceinline__ void gload_lds16(const void* g, void* l) {
  __builtin_amdgcn_global_load_lds(
      (const __attribute__((address_space(1))) unsigned int*)g,
      (__attribute__((address_space(3))) unsigned int*)l, 16, 0, 0);
}

// Kernel 1: L2-normalize rows, emit bf16 hi/lo planes, compact censor==1 rows.
__global__ __launch_bounds__(256) void ck_normalize(
    const float* __restrict__ emb, const int* __restrict__ censor,
    short* __restrict__ Zh, short* __restrict__ Zl,
    int* __restrict__ rowlist, int* __restrict__ cnt)
{
  const int lane = threadIdx.x & 63;
  const int row  = (blockIdx.x << 2) + (threadIdx.x >> 6);  // 1 wave / row
  const float e0 = emb[row * DDIM + lane];
  const float e1 = emb[row * DDIM + 64 + lane];
  float ss = e0 * e0 + e1 * e1;
#pragma unroll
  for (int m = 1; m < 64; m <<= 1) ss += __shfl_xor(ss, m, 64);
  const float inv = 1.0f / fmaxf(sqrtf(ss), 1e-12f);
  const float z0 = e0 * inv, z1 = e1 * inv;
  const short h0 = f2bf(z0), h1 = f2bf(z1);
  Zh[row * DDIM + lane]      = h0;
  Zh[row * DDIM + 64 + lane] = h1;
  Zl[row * DDIM + lane]      = f2bf(z0 - bf2f(h0));
  Zl[row * DDIM + 64 + lane] = f2bf(z1 - bf2f(h1));
  if (lane == 0 && censor[row] == 1) {
    const int p = atomicAdd(cnt, 1);
    rowlist[p] = row;
  }
}

// Kernel 2: MFMA sim + masked exp-sum reductions.
// Block = 128(i, compacted) x 128(j) tile; 4 waves, each a 64x64 quadrant of
// 4x4 mfma_f32_16x16x32_bf16 tiles. 3 plane passes: Ah*Bh + Ah*Bl + Al*Bh.
// B hi/lo planes in LDS (64 KB), XOR-swizzled at 16B-chunk granularity via the
// *global source address* permutation (global_load_lds dest is lane-contiguous).
// A fragments loaded directly from global (L2) into registers via rowlist.
__global__ __launch_bounds__(256, 2) void ck_main(
    const short* __restrict__ Zh, const short* __restrict__ Zl,
    const int* __restrict__ rowlist, const int* __restrict__ cntp,
    const int* __restrict__ times, float* __restrict__ Sd, float* __restrict__ Sn)
{
  __shared__ short Bh[128 * 128];   // 32 KB
  __shared__ short Bl[128 * 128];   // 32 KB (total exactly 64 KB)

  const int cnt = *cntp;
  const int ibase = (blockIdx.x >> 6) * 128;      // compacted i-tile base
  if (ibase >= cnt) return;
  const int jbase = (blockIdx.x & 63) * 128;

  const int tid  = threadIdx.x;
  const int w    = tid >> 6;        // wave 0..3
  const int lane = tid & 63;
  const int half = lane >> 4;       // 0..3
  const int ll   = lane & 15;
  const int ih = (w >> 1) * 64;     // wave's local i quadrant
  const int jq = (w & 1) * 64;      // wave's local j quadrant

  // ---- stage B planes: wave {0,1}->Bh halves, {2,3}->Bl halves ----
  {
    const short* src = (w < 2) ? Zh : Zl;
    short* dst = (w < 2) ? Bh : Bl;
    const int rhalf = (w & 1) * 64;
#pragma unroll
    for (int t = 0; t < 16; ++t) {
      const int row = rhalf + t * 4 + half;          // local j row this lane fills
      const int c = ll ^ (row & 15);                 // logical 16B chunk for phys slot ll
      const short* g = src + (size_t)(jbase + row) * DDIM + c * 8;
      gload_lds16(g, (char*)dst + rhalf * 256 + t * 1024);  // + lane*16 implicit
    }
  }

  // ---- A-row ids for this lane (A-frag rows m = ll) ----
  int rA[4];
#pragma unroll
  for (int a = 0; a < 4; ++a) {
    int idx = ibase + ih + a * 16 + ll;
    if (idx >= cnt) idx = cnt - 1;   // duplicate a valid row; masked at epilogue
    rA[a] = rowlist[idx];
  }

  f32x4 acc[4][4];
#pragma unroll
  for (int a = 0; a < 4; ++a)
#pragma unroll
    for (int b = 0; b < 4; ++b) acc[a][b] = (f32x4){0.f, 0.f, 0.f, 0.f};

  // A hi fragments: frag(a,kc) = 8 bf16 at row rA[a], k = kc*32 + half*8
  bf16x8 af[4][4];
#pragma unroll
  for (int a = 0; a < 4; ++a) {
    const short* base = Zh + (size_t)rA[a] * DDIM + half * 8;
#pragma unroll
    for (int kc = 0; kc < 4; ++kc) af[a][kc] = *(const bf16x8*)(base + kc * 32);
  }

  // B LDS addressing: byte = row*256 + ((kc*4+half)^ll)*16, row = jq+b*16+ll
  int rowoff[4], coff[4];
#pragma unroll
  for (int b = 0; b < 4; ++b) rowoff[b] = (jq + b * 16 + ll) * 256;
#pragma unroll
  for (int kc = 0; kc < 4; ++kc) coff[kc] = ((kc * 4 + half) ^ ll) * 16;

  __syncthreads();   // B planes resident (vmcnt(0) drained by barrier)

  // passes 1,2: Ah*Bh then Ah*Bl
#pragma unroll
  for (int p = 0; p < 2; ++p) {
    const char* Bp = (const char*)(p == 0 ? Bh : Bl);
#pragma unroll
    for (int kc = 0; kc < 4; ++kc) {
      bf16x8 bv[4];
#pragma unroll
      for (int b = 0; b < 4; ++b)
        bv[b] = *(const bf16x8*)(Bp + rowoff[b] + coff[kc]);
#pragma unroll
      for (int a = 0; a < 4; ++a)
#pragma unroll
        for (int b = 0; b < 4; ++b)
          acc[a][b] = __builtin_amdgcn_mfma_f32_16x16x32_bf16(
              af[a][kc], bv[b], acc[a][b], 0, 0, 0);
    }
  }

  // reload A lo frags; pass 3: Al*Bh
#pragma unroll
  for (int a = 0; a < 4; ++a) {
    const short* base = Zl + (size_t)rA[a] * DDIM + half * 8;
#pragma unroll
    for (int kc = 0; kc < 4; ++kc) af[a][kc] = *(const bf16x8*)(base + kc * 32);
  }
#pragma unroll
  for (int kc = 0; kc < 4; ++kc) {
    bf16x8 bv[4];
#pragma unroll
    for (int b = 0; b < 4; ++b)
      bv[b] = *(const bf16x8*)((const char*)Bh + rowoff[b] + coff[kc]);
#pragma unroll
    for (int a = 0; a < 4; ++a)
#pragma unroll
      for (int b = 0; b < 4; ++b)
        acc[a][b] = __builtin_amdgcn_mfma_f32_16x16x32_bf16(
            af[a][kc], bv[b], acc[a][b], 0, 0, 0);
  }

  // ---- epilogue: C/D layout col=ll -> j, row=half*4+reg -> i (m89/m91) ----
  int jg[4], tJ[4];
#pragma unroll
  for (int b = 0; b < 4; ++b) {
    jg[b] = jbase + jq + b * 16 + ll;
    tJ[b] = times[jg[b]];
  }

#pragma unroll
  for (int a = 0; a < 4; ++a) {
#pragma unroll
    for (int r = 0; r < 4; ++r) {
      const int idx = ibase + ih + a * 16 + half * 4 + r;  // output-row compacted idx
      const bool vi = (idx < cnt);
      const int gi = rowlist[vi ? idx : 0];
      const int ti = times[gi];
      float sd = 0.f, sn = 0.f;
#pragma unroll
      for (int b = 0; b < 4; ++b) {
        const float s = acc[a][b][r] * 10.0f;     // cos/T
        float pv = __expf(s - 10.0f);             // fixed-offset LSE term
        if (gi == jg[b]) pv = 0.f;                // diagonal mask
        sd += pv;
        int td = ti - tJ[b];
        td = td < 0 ? -td : td;
        if (td < 365) sn += pv;                   // positive mask
      }
#pragma unroll
      for (int m = 1; m <= 8; m <<= 1) {          // reduce over ll (bits 0..3)
        sd += __shfl_xor(sd, m, 64);
        sn += __shfl_xor(sn, m, 64);
      }
      if (ll == 0 && vi) {
        atomicAdd(&Sd[gi], sd);
        atomicAdd(&Sn[gi], sn);
      }
    }
  }
}

// Kernel 3: per-row loss = log(Sd) - log(Sn); deterministic final reduce.
__global__ __launch_bounds__(1024) void ck_finalize(
    const float* __restrict__ Sd, const float* __restrict__ Sn,
    const int* __restrict__ censor, float* __restrict__ out)
{
  __shared__ float ssum[1024];
  __shared__ float scnt[1024];
  const int tid = threadIdx.x;
  float lsum = 0.f, lcnt = 0.f;
  for (int r = tid; r < BDIM; r += 1024) {
    const float n = Sn[r];
    if (censor[r] == 1 && n > 0.f) {
      lsum += logf(Sd[r]) - logf(n);
      lcnt += 1.f;
    }
  }
  ssum[tid] = lsum;
  scnt[tid] = lcnt;
  __syncthreads();
  for (int s = 512; s > 0; s >>= 1) {
    if (tid < s) { ssum[tid] += ssum[tid + s]; scnt[tid] += scnt[tid + s]; }
    __syncthreads();
  }
  if (tid == 0) out[0] = (scnt[0] > 0.f) ? ssum[0] / fmaxf(scnt[0], 1.f) : 0.f;
}

extern "C" void kernel_launch(void* const* d_in, const int* in_sizes, int n_in,
                              void* d_out, int out_size, void* d_ws, size_t ws_size,
                              hipStream_t stream) {
  const float* emb  = (const float*)d_in[0];
  const int* times  = (const int*)d_in[1];
  const int* censor = (const int*)d_in[2];
  float* out = (float*)d_out;

  char* ws = (char*)d_ws;
  short* Zh    = (short*)(ws + ZH_OFF);
  short* Zl    = (short*)(ws + ZL_OFF);
  int* rowlist = (int*)(ws + ROWLIST_OFF);
  float* Sd    = (float*)(ws + SD_OFF);
  float* Sn    = (float*)(ws + SN_OFF);
  int* cnt     = (int*)(ws + CNT_OFF);

  hipMemsetAsync(ws + SD_OFF, 0, BDIM * 4 * 2 + 4, stream);  // Sd, Sn, cnt
  ck_normalize<<<BDIM / 4, 256, 0, stream>>>(emb, censor, Zh, Zl, rowlist, cnt);
  ck_main<<<64 * 64, 256, 0, stream>>>(Zh, Zl, rowlist, cnt, times, Sd, Sn);
  ck_finalize<<<1, 1024, 0, stream>>>(Sd, Sn, censor, out);
}

// Round 3
// 196.904 us; speedup vs baseline: 1.4972x; 1.3769x over previous
//
#include <hip/hip_runtime.h>
#include <cstdint>

#define BDIM 8192
#define DDIM 128
#define JSPLIT 16
#define JTILES 4                       // j-tiles of 128 per block (512 j/block)

// ws layout (bytes)
#define ZH_OFF 0
#define ZL_OFF (BDIM * DDIM * 2)                  // 2 MB
#define ROWLIST_OFF (ZL_OFF + BDIM * DDIM * 2)    // 4 MB
#define CNT_OFF (ROWLIST_OFF + BDIM * 4)          // 4 MB + 32 KB
#define P_OFF (ROWLIST_OFF + 65536)               // 4 MB + 64 KB
#define PART_OFF (P_OFF + JSPLIT * BDIM * 8)      // + 1 MB  (32 float2)

typedef __attribute__((ext_vector_type(8))) short bf16x8;   // 8 bf16 = 4 VGPRs
typedef __attribute__((ext_vector_type(4))) float f32x4;

__device__ __forceinline__ short f2bf(float f) {          // RTN-even fp32->bf16
  unsigned u = __float_as_uint(f);
  unsigned r = (u + 0x7fffu + ((u >> 16) & 1u)) >> 16;
  return (short)r;
}
__device__ __forceinline__ float bf2f(short h) {
  return __uint_as_float(((unsigned)(unsigned short)h) << 16);
}
__device__ __forceinline__ void gload_lds16(const void* g, void* l) {
  __builtin_amdgcn_global_load_lds(
      (const __attribute__((address_space(1))) unsigned int*)g,
      (__attribute__((address_space(3))) unsigned int*)l, 16, 0, 0);
}

// Kernel 1: L2-normalize rows, emit bf16 hi/lo planes, compact censor==1 rows.
__global__ __launch_bounds__(256) void ck_normalize(
    const float* __restrict__ emb, const int* __restrict__ censor,
    short* __restrict__ Zh, short* __restrict__ Zl,
    int* __restrict__ rowlist, int* __restrict__ cnt)
{
  const int lane = threadIdx.x & 63;
  const int row  = (blockIdx.x << 2) + (threadIdx.x >> 6);  // 1 wave / row
  const float e0 = emb[row * DDIM + lane];
  const float e1 = emb[row * DDIM + 64 + lane];
  float ss = e0 * e0 + e1 * e1;
#pragma unroll
  for (int m = 1; m < 64; m <<= 1) ss += __shfl_xor(ss, m, 64);
  const float inv = 1.0f / fmaxf(sqrtf(ss), 1e-12f);
  const float z0 = e0 * inv, z1 = e1 * inv;
  const short h0 = f2bf(z0), h1 = f2bf(z1);
  Zh[row * DDIM + lane]      = h0;
  Zh[row * DDIM + 64 + lane] = h1;
  Zl[row * DDIM + lane]      = f2bf(z0 - bf2f(h0));
  Zl[row * DDIM + 64 + lane] = f2bf(z1 - bf2f(h1));
  if (lane == 0 && censor[row] == 1) {
    const int p = atomicAdd(cnt, 1);
    rowlist[p] = row;
  }
}

// Kernel 2: MFMA sim + masked exp-sum partials. 128(i) x 512(j) per block via
// a 4-tile j-loop; sd/sn accumulate in registers across the loop; NO global
// atomics — per-block partials stored dense to P[js][compacted_row].
__global__ __launch_bounds__(256, 2) void ck_main(
    const short* __restrict__ Zh, const short* __restrict__ Zl,
    const int* __restrict__ rowlist, const int* __restrict__ cntp,
    const int* __restrict__ times, float2* __restrict__ P2)
{
  __shared__ short Bh[128 * 128];   // 32 KB
  __shared__ short Bl[128 * 128];   // 32 KB (total exactly 64 KB)

  const int cnt = *cntp;
  const int it = blockIdx.x & 63;          // i-tile slot (compacted space)
  const int js = blockIdx.x >> 6;          // j-split 0..15
  const int ibase = it * 128;
  if (ibase >= cnt) return;

  const int tid  = threadIdx.x;
  const int w    = tid >> 6;
  const int lane = tid & 63;
  const int half = lane >> 4;
  const int ll   = lane & 15;
  const int ih = (w >> 1) * 64;            // wave's local i quadrant
  const int jq = (w & 1) * 64;             // wave's local j quadrant

  // A-frag row ids (MFMA A rows m = ll)
  int rA[4];
#pragma unroll
  for (int a = 0; a < 4; ++a) {
    int idx = ibase + ih + a * 16 + ll;
    if (idx >= cnt) idx = cnt - 1;         // duplicate valid row; masked later
    rA[a] = rowlist[idx];
  }

  // epilogue row metadata (C/D rows = half*4 + r)
  int giE[4][4], tiE[4][4];
#pragma unroll
  for (int a = 0; a < 4; ++a)
#pragma unroll
    for (int r = 0; r < 4; ++r) {
      const int idx = ibase + ih + a * 16 + half * 4 + r;
      const bool vi = (idx < cnt);
      const int gi = rowlist[vi ? idx : 0];
      giE[a][r] = vi ? gi : -1;            // -1 never matches a j index
      tiE[a][r] = vi ? times[gi] : -1000000;
    }

  // A hi fragments, persistent across the j-loop
  bf16x8 af[4][4];
#pragma unroll
  for (int a = 0; a < 4; ++a) {
    const short* base = Zh + (size_t)rA[a] * DDIM + half * 8;
#pragma unroll
    for (int kc = 0; kc < 4; ++kc) af[a][kc] = *(const bf16x8*)(base + kc * 32);
  }

  // B LDS addressing: byte = row*256 + ((kc*4+half)^ll)*16
  int rowoff[4], coff[4];
#pragma unroll
  for (int b = 0; b < 4; ++b) rowoff[b] = (jq + b * 16 + ll) * 256;
#pragma unroll
  for (int kc = 0; kc < 4; ++kc) coff[kc] = ((kc * 4 + half) ^ ll) * 16;

  float sd[4][4] = {{0.f}}, sn[4][4] = {{0.f}};

  for (int jt = 0; jt < JTILES; ++jt) {
    const int jbase = js * (JTILES * 128) + jt * 128;

    __syncthreads();   // previous tile's LDS readers done
    {  // stage B planes: waves {0,1}->Bh halves, {2,3}->Bl halves, XOR-swizzled
      const short* src = (w < 2) ? Zh : Zl;
      short* dst = (w < 2) ? Bh : Bl;
      const int rhalf = (w & 1) * 64;
#pragma unroll
      for (int t = 0; t < 16; ++t) {
        const int row = rhalf + t * 4 + half;
        const int c = ll ^ (row & 15);
        const short* g = src + (size_t)(jbase + row) * DDIM + c * 8;
        gload_lds16(g, (char*)dst + rhalf * 256 + t * 1024);  // +lane*16 implicit
      }
    }
    __syncthreads();   // B resident

    f32x4 acc[4][4];
#pragma unroll
    for (int a = 0; a < 4; ++a)
#pragma unroll
      for (int b = 0; b < 4; ++b) acc[a][b] = (f32x4){0.f, 0.f, 0.f, 0.f};

    // passes 1,2: Ah*Bh then Ah*Bl
#pragma unroll
    for (int p = 0; p < 2; ++p) {
      const char* Bp = (const char*)(p == 0 ? Bh : Bl);
#pragma unroll
      for (int kc = 0; kc < 4; ++kc) {
        bf16x8 bv[4];
#pragma unroll
        for (int b = 0; b < 4; ++b)
          bv[b] = *(const bf16x8*)(Bp + rowoff[b] + coff[kc]);
#pragma unroll
        for (int a = 0; a < 4; ++a)
#pragma unroll
          for (int b = 0; b < 4; ++b)
            acc[a][b] = __builtin_amdgcn_mfma_f32_16x16x32_bf16(
                af[a][kc], bv[b], acc[a][b], 0, 0, 0);
      }
    }
    // pass 3: Al*Bh (A lo reloaded; L1-hits after first iteration)
#pragma unroll
    for (int kc = 0; kc < 4; ++kc) {
      bf16x8 bv[4];
#pragma unroll
      for (int b = 0; b < 4; ++b)
        bv[b] = *(const bf16x8*)((const char*)Bh + rowoff[b] + coff[kc]);
#pragma unroll
      for (int a = 0; a < 4; ++a) {
        const bf16x8 al =
            *(const bf16x8*)(Zl + (size_t)rA[a] * DDIM + half * 8 + kc * 32);
#pragma unroll
        for (int b = 0; b < 4; ++b)
          acc[a][b] = __builtin_amdgcn_mfma_f32_16x16x32_bf16(
              al, bv[b], acc[a][b], 0, 0, 0);
      }
    }

    // epilogue: accumulate masked exp-sums in registers (no reduce yet)
    int jg[4], tJ[4];
#pragma unroll
    for (int b = 0; b < 4; ++b) {
      jg[b] = jbase + jq + b * 16 + ll;
      tJ[b] = times[jg[b]];
    }
#pragma unroll
    for (int a = 0; a < 4; ++a)
#pragma unroll
      for (int r = 0; r < 4; ++r) {
        const int gi = giE[a][r], ti = tiE[a][r];
        float d = 0.f, n = 0.f;
#pragma unroll
        for (int b = 0; b < 4; ++b) {
          const float s = acc[a][b][r] * 10.0f;
          float pv = __expf(s - 10.0f);    // fixed-offset LSE term, in [e^-20,1]
          if (gi == jg[b]) pv = 0.f;       // diagonal mask
          d += pv;
          int td = ti - tJ[b];
          td = td < 0 ? -td : td;
          if (td < 365) n += pv;           // positive mask
        }
        sd[a][r] += d;
        sn[a][r] += n;
      }
  }

  // deferred reduce over ll (lane bits 0..3), once per block
#pragma unroll
  for (int a = 0; a < 4; ++a)
#pragma unroll
    for (int r = 0; r < 4; ++r) {
      float d = sd[a][r], n = sn[a][r];
#pragma unroll
      for (int m = 1; m <= 8; m <<= 1) {
        d += __shfl_xor(d, m, 64);
        n += __shfl_xor(n, m, 64);
      }
      sd[a][r] = d;
      sn[a][r] = n;
    }

  // combine the two waves sharing each i-quadrant via LDS (reuse Bh), then
  // one coalesced float2 store per row — zero global atomics.
  __syncthreads();
  float* comb = (float*)Bh;                // [128 rows][2 wave-pair][2 d/n]
  if (ll == 0) {
#pragma unroll
    for (int a = 0; a < 4; ++a)
#pragma unroll
      for (int r = 0; r < 4; ++r) {
        const int row = ih + a * 16 + half * 4 + r;
        comb[row * 4 + (w & 1) * 2 + 0] = sd[a][r];
        comb[row * 4 + (w & 1) * 2 + 1] = sn[a][r];
      }
  }
  __syncthreads();
  if (tid < 128) {
    const int row = tid, idx = ibase + row;
    if (idx < cnt) {
      const float d = comb[row * 4 + 0] + comb[row * 4 + 2];
      const float n = comb[row * 4 + 1] + comb[row * 4 + 3];
      P2[js * BDIM + idx] = make_float2(d, n);
    }
  }
}

// Finalize A: per compacted row, sum partials over the 16 j-splits, compute
// log(Sd)-log(Sn) where Sn>0; block-reduce (sum, count) -> part[32].
__global__ __launch_bounds__(256) void ck_fin_a(
    const float2* __restrict__ P2, const int* __restrict__ cntp,
    float2* __restrict__ part)
{
  const int cnt = *cntp;
  const int tid = threadIdx.x;
  const int r = blockIdx.x * 256 + tid;
  float lsum = 0.f, lcnt = 0.f;
  if (r < cnt) {
    float d = 0.f, n = 0.f;
#pragma unroll
    for (int js = 0; js < JSPLIT; ++js) {
      const float2 v = P2[js * BDIM + r];
      d += v.x;
      n += v.y;
    }
    if (n > 0.f) { lsum = logf(d) - logf(n); lcnt = 1.f; }
  }
  __shared__ float s1[256], s2[256];
  s1[tid] = lsum; s2[tid] = lcnt;
  __syncthreads();
  for (int s = 128; s > 0; s >>= 1) {
    if (tid < s) { s1[tid] += s1[tid + s]; s2[tid] += s2[tid + s]; }
    __syncthreads();
  }
  if (tid == 0) part[blockIdx.x] = make_float2(s1[0], s2[0]);
}

// Finalize B: single wave reduces the 32 block partials.
__global__ __launch_bounds__(64) void ck_fin_b(
    const float2* __restrict__ part, float* __restrict__ out)
{
  const int t = threadIdx.x;
  float s = 0.f, c = 0.f;
  if (t < 32) { const float2 v = part[t]; s = v.x; c = v.y; }
#pragma unroll
  for (int m = 1; m < 64; m <<= 1) {
    s += __shfl_xor(s, m, 64);
    c += __shfl_xor(c, m, 64);
  }
  if (t == 0) out[0] = (c > 0.f) ? s / fmaxf(c, 1.f) : 0.f;
}

extern "C" void kernel_launch(void* const* d_in, const int* in_sizes, int n_in,
                              void* d_out, int out_size, void* d_ws, size_t ws_size,
                              hipStream_t stream) {
  const float* emb  = (const float*)d_in[0];
  const int* times  = (const int*)d_in[1];
  const int* censor = (const int*)d_in[2];
  float* out = (float*)d_out;

  char* ws = (char*)d_ws;
  short* Zh    = (short*)(ws + ZH_OFF);
  short* Zl    = (short*)(ws + ZL_OFF);
  int* rowlist = (int*)(ws + ROWLIST_OFF);
  int* cnt     = (int*)(ws + CNT_OFF);
  float2* P2   = (float2*)(ws + P_OFF);
  float2* part = (float2*)(ws + PART_OFF);

  hipMemsetAsync(cnt, 0, 4, stream);
  ck_normalize<<<BDIM / 4, 256, 0, stream>>>(emb, censor, Zh, Zl, rowlist, cnt);
  ck_main<<<64 * JSPLIT, 256, 0, stream>>>(Zh, Zl, rowlist, cnt, times, P2);
  ck_fin_a<<<BDIM / 256, 256, 0, stream>>>(P2, cnt, part);
  ck_fin_b<<<1, 64, 0, stream>>>(part, out);
}

// Round 4
// 131.316 us; speedup vs baseline: 2.2449x; 1.4995x over previous
//
#include <hip/hip_runtime.h>
#include <cstdint>

#define BDIM 8192
#define DDIM 128
#define JS 32                 // j-splits: each wave covers 8192/32 = 256 j
#define NIU 128               // i-unit slots of 64 compacted rows (covers cnt<=8192)

// ws layout (bytes)
#define ZH_OFF 0
#define ZL_OFF (2 * 1024 * 1024)
#define RL_OFF (4 * 1024 * 1024)
#define CNT_OFF (RL_OFF + BDIM * 4)
#define P_OFF (RL_OFF + 65536)                 // float2 P2[BDIM][JS] = 2 MB
#define PART_OFF (P_OFF + BDIM * JS * 8)       // float2 part[32]

typedef __attribute__((ext_vector_type(8))) short bf16x8;   // 8 bf16 = 4 VGPRs
typedef __attribute__((ext_vector_type(4))) float f32x4;

__device__ __forceinline__ short f2bf(float f) {            // RTN-even fp32->bf16
  unsigned u = __float_as_uint(f);
  unsigned r = (u + 0x7fffu + ((u >> 16) & 1u)) >> 16;
  return (short)r;
}
__device__ __forceinline__ float bf2f(short h) {
  return __uint_as_float(((unsigned)(unsigned short)h) << 16);
}

// Fragment-tiled Z layout (shorts): element (row,k) at
//   (row>>4)*2048 + (k>>5)*512 + ((k>>3)&3)*128 + (row&15)*8 + (k&7)
// so an MFMA fragment load (16 rows x 8 k) is ONE contiguous 1 KB wave load.

// Kernel 1: compact censor==1 rows via block prefix-scan. 1 block, NO atomics.
__global__ __launch_bounds__(1024) void ck_compact(
    const int* __restrict__ censor, int* __restrict__ rowlist, int* __restrict__ cnt)
{
  const int t = threadIdx.x;
  const int lane = t & 63, wv = t >> 6;    // 16 waves
  int flags[8], loc = 0;
  const int base = t * 8;
#pragma unroll
  for (int u = 0; u < 8; ++u) { flags[u] = (censor[base + u] == 1); loc += flags[u]; }
  int sc = loc;                             // inclusive wave scan
#pragma unroll
  for (int m = 1; m < 64; m <<= 1) {
    const int v = __shfl_up(sc, m, 64);
    if (lane >= m) sc += v;
  }
  __shared__ int wtot[16], woff[16];
  if (lane == 63) wtot[wv] = sc;
  __syncthreads();
  if (t == 0) {
    int run = 0;
#pragma unroll
    for (int i = 0; i < 16; ++i) { woff[i] = run; run += wtot[i]; }
  }
  __syncthreads();
  int off = woff[wv] + sc - loc;            // exclusive offset for this thread
#pragma unroll
  for (int u = 0; u < 8; ++u)
    if (flags[u]) rowlist[off++] = base + u;
  if (t == 1023) cnt[0] = off;              // == total count
}

// Kernel 2: L2-normalize + bf16 hi/lo split + write fragment-tiled Zh/Zl.
// Block handles one 16-row tile; pure streaming, no atomics.
__global__ __launch_bounds__(256) void ck_normalize(
    const float* __restrict__ emb, short* __restrict__ ZhT, short* __restrict__ ZlT)
{
  __shared__ float zl[16][132];   // +4 pad: writer-phase reads stride 132 -> 2-way max
  __shared__ float pr[16][16];
  __shared__ float inv[16];
  const int t = threadIdx.x, R = blockIdx.x;
  const int r16 = t >> 4, seg = t & 15;
  const float4* src = (const float4*)(emb + (size_t)(R * 16 + r16) * DDIM + seg * 8);
  const float4 v0 = src[0], v1 = src[1];
  float* zr = &zl[r16][seg * 8];
  zr[0] = v0.x; zr[1] = v0.y; zr[2] = v0.z; zr[3] = v0.w;
  zr[4] = v1.x; zr[5] = v1.y; zr[6] = v1.z; zr[7] = v1.w;
  pr[r16][seg] = v0.x * v0.x + v0.y * v0.y + v0.z * v0.z + v0.w * v0.w +
                 v1.x * v1.x + v1.y * v1.y + v1.z * v1.z + v1.w * v1.w;
  __syncthreads();
  if (t < 16) {
    float ss = 0.f;
#pragma unroll
    for (int s = 0; s < 16; ++s) ss += pr[t][s];
    inv[t] = 1.0f / fmaxf(sqrtf(ss), 1e-12f);   // F.normalize semantics
  }
  __syncthreads();
  // writer mapping: t = kc*64 + half*16 + r16w  -> tiled offset R*2048 + t*8
  const int kc = t >> 6, half = (t >> 4) & 3, r16w = t & 15;
  const float iv = inv[r16w];
  const float* zs = &zl[r16w][(kc * 4 + half) * 8];
  short hs[8], ls[8];
#pragma unroll
  for (int j = 0; j < 8; ++j) {
    const float z = zs[j] * iv;
    const short h = f2bf(z);
    hs[j] = h;
    ls[j] = f2bf(z - bf2f(h));
  }
  const int dst = R * 2048 + t * 8;
  *(bf16x8*)(ZhT + dst) = *(const bf16x8*)hs;
  *(bf16x8*)(ZlT + dst) = *(const bf16x8*)ls;
}

// Kernel 3: register-streaming MFMA sim + masked exp-sums.
// One wave = 64 compacted i-rows x 256 j. A hi+lo frags resident in VGPRs;
// B frags streamed straight from global (L2-resident, 1 KB contiguous/load).
// ZERO LDS, ZERO barriers, ZERO atomics. Partials to dense P2[idx][js].
__global__ __launch_bounds__(256) void ck_main(
    const short* __restrict__ ZhT, const short* __restrict__ ZlT,
    const int* __restrict__ rowlist, const int* __restrict__ cntp,
    const int* __restrict__ times, float2* __restrict__ P2)
{
  const int cnt = *cntp;
  const int wid = blockIdx.x * 4 + (threadIdx.x >> 6);
  const int iu = wid >> 5;                  // i-unit (64 rows)
  const int js = wid & (JS - 1);            // j-split
  if (iu * 64 >= cnt) return;
  const int lane = threadIdx.x & 63;
  const int half = lane >> 4;               // 0..3
  const int ll = lane & 15;

  // A-row gather (A-operand rows m = ll)
  int rbase[4];
#pragma unroll
  for (int a = 0; a < 4; ++a) {
    int c = iu * 64 + a * 16 + ll;
    if (c >= cnt) c = cnt - 1;              // duplicate valid row; masked at store
    const int r = rowlist[c];
    rbase[a] = (r >> 4) * 2048 + (r & 15) * 8;
  }
  bf16x8 ah[4][4], al[4][4];                // 128 VGPRs, resident
#pragma unroll
  for (int a = 0; a < 4; ++a)
#pragma unroll
    for (int kc = 0; kc < 4; ++kc) {
      ah[a][kc] = *(const bf16x8*)(ZhT + rbase[a] + kc * 512 + half * 128);
      al[a][kc] = *(const bf16x8*)(ZlT + rbase[a] + kc * 512 + half * 128);
    }

  // epilogue row metadata (C/D rows = half*4 + r)
  int giE[4][4], tiE[4][4];
#pragma unroll
  for (int a = 0; a < 4; ++a)
#pragma unroll
    for (int r = 0; r < 4; ++r) {
      const int idx = iu * 64 + a * 16 + half * 4 + r;
      const bool vi = (idx < cnt);
      const int gi = vi ? rowlist[idx] : -1;
      giE[a][r] = vi ? gi : -1;
      tiE[a][r] = vi ? times[gi] : -1000000;
    }

  float sd[4][4] = {{0.f}}, sn[4][4] = {{0.f}};

  for (int st = 0; st < 4; ++st) {          // 4 j-steps of 64
    const int jb = js * 256 + st * 64;
    const int jR = jb >> 4;
    f32x4 acc[4][4];
#pragma unroll
    for (int a = 0; a < 4; ++a)
#pragma unroll
      for (int b = 0; b < 4; ++b) acc[a][b] = (f32x4){0.f, 0.f, 0.f, 0.f};

#pragma unroll
    for (int kc = 0; kc < 4; ++kc) {
      bf16x8 bh[4], bl[4];
#pragma unroll
      for (int b = 0; b < 4; ++b) {
        const int o = (jR + b) * 2048 + kc * 512 + lane * 8;  // contiguous 1 KB/wave
        bh[b] = *(const bf16x8*)(ZhT + o);
        bl[b] = *(const bf16x8*)(ZlT + o);
      }
#pragma unroll
      for (int a = 0; a < 4; ++a)
#pragma unroll
        for (int b = 0; b < 4; ++b)
          acc[a][b] = __builtin_amdgcn_mfma_f32_16x16x32_bf16(ah[a][kc], bh[b], acc[a][b], 0, 0, 0);
#pragma unroll
      for (int a = 0; a < 4; ++a)
#pragma unroll
        for (int b = 0; b < 4; ++b)
          acc[a][b] = __builtin_amdgcn_mfma_f32_16x16x32_bf16(ah[a][kc], bl[b], acc[a][b], 0, 0, 0);
#pragma unroll
      for (int a = 0; a < 4; ++a)
#pragma unroll
        for (int b = 0; b < 4; ++b)
          acc[a][b] = __builtin_amdgcn_mfma_f32_16x16x32_bf16(al[a][kc], bh[b], acc[a][b], 0, 0, 0);
    }

    // epilogue: fixed-offset exp-sums; s = cos/T in [-10,10], exp(s-10) in [e^-20,1]
    int jg[4], tJ[4];
#pragma unroll
    for (int b = 0; b < 4; ++b) {
      jg[b] = jb + b * 16 + ll;
      tJ[b] = times[jg[b]];
    }
#pragma unroll
    for (int a = 0; a < 4; ++a)
#pragma unroll
      for (int r = 0; r < 4; ++r) {
        const int gi = giE[a][r], ti = tiE[a][r];
        float d = 0.f, n = 0.f;
#pragma unroll
        for (int b = 0; b < 4; ++b) {
          const float s = acc[a][b][r] * 10.0f;
          float pv = __expf(s - 10.0f);
          if (gi == jg[b]) pv = 0.f;         // diagonal mask
          d += pv;
          int td = ti - tJ[b];
          td = td < 0 ? -td : td;
          if (td < 365) n += pv;             // positive mask
        }
        sd[a][r] += d;
        sn[a][r] += n;
      }
  }

  // reduce over ll (lane bits 0..3); store one float2 per valid row
#pragma unroll
  for (int a = 0; a < 4; ++a)
#pragma unroll
    for (int r = 0; r < 4; ++r) {
      float d = sd[a][r], n = sn[a][r];
#pragma unroll
      for (int m = 1; m <= 8; m <<= 1) {
        d += __shfl_xor(d, m, 64);
        n += __shfl_xor(n, m, 64);
      }
      const int idx = iu * 64 + a * 16 + half * 4 + r;
      if (ll == 0 && idx < cnt) P2[idx * JS + js] = make_float2(d, n);
    }
}

// Kernel 4: per-row combine over JS splits + log-ratio; block partials.
__global__ __launch_bounds__(256) void ck_fin_a(
    const float2* __restrict__ P2, const int* __restrict__ cntp,
    float2* __restrict__ part)
{
  const int cnt = *cntp;
  const int t = threadIdx.x;
  const int idx = blockIdx.x * 256 + t;
  float lsum = 0.f, lcnt = 0.f;
  if (idx < cnt) {
    const float4* p = (const float4*)(P2 + (size_t)idx * JS);  // 256 B contiguous
    float d = 0.f, n = 0.f;
#pragma unroll
    for (int u = 0; u < 16; ++u) {
      const float4 v = p[u];
      d += v.x + v.z;
      n += v.y + v.w;
    }
    if (n > 0.f) { lsum = logf(d) - logf(n); lcnt = 1.f; }
  }
  __shared__ float s1[256], s2[256];
  s1[t] = lsum; s2[t] = lcnt;
  __syncthreads();
  for (int s = 128; s > 0; s >>= 1) {
    if (t < s) { s1[t] += s1[t + s]; s2[t] += s2[t + s]; }
    __syncthreads();
  }
  if (t == 0) part[blockIdx.x] = make_float2(s1[0], s2[0]);
}

// Kernel 5: final reduce of 32 partials.
__global__ __launch_bounds__(64) void ck_fin_b(
    const float2* __restrict__ part, float* __restrict__ out)
{
  const int t = threadIdx.x;
  float s = 0.f, c = 0.f;
  if (t < 32) { const float2 v = part[t]; s = v.x; c = v.y; }
#pragma unroll
  for (int m = 1; m < 64; m <<= 1) {
    s += __shfl_xor(s, m, 64);
    c += __shfl_xor(c, m, 64);
  }
  if (t == 0) out[0] = (c > 0.f) ? s / fmaxf(c, 1.f) : 0.f;
}

extern "C" void kernel_launch(void* const* d_in, const int* in_sizes, int n_in,
                              void* d_out, int out_size, void* d_ws, size_t ws_size,
                              hipStream_t stream) {
  const float* emb  = (const float*)d_in[0];
  const int* times  = (const int*)d_in[1];
  const int* censor = (const int*)d_in[2];
  float* out = (float*)d_out;

  char* ws = (char*)d_ws;
  short* ZhT   = (short*)(ws + ZH_OFF);
  short* ZlT   = (short*)(ws + ZL_OFF);
  int* rowlist = (int*)(ws + RL_OFF);
  int* cnt     = (int*)(ws + CNT_OFF);
  float2* P2   = (float2*)(ws + P_OFF);
  float2* part = (float2*)(ws + PART_OFF);

  ck_compact<<<1, 1024, 0, stream>>>(censor, rowlist, cnt);
  ck_normalize<<<BDIM / 16, 256, 0, stream>>>(emb, ZhT, ZlT);
  ck_main<<<NIU * JS / 4, 256, 0, stream>>>(ZhT, ZlT, rowlist, cnt, times, P2);
  ck_fin_a<<<BDIM / 256, 256, 0, stream>>>(P2, cnt, part);
  ck_fin_b<<<1, 64, 0, stream>>>(part, out);
}